// Round 18
// baseline (67.574 us; speedup 1.0000x reference)
//
#include <hip/hip_runtime.h>

#define NB    8
#define NH    16384
#define NL    2048
#define F_HR  64
#define F_LR  128
#define OUT_COLS 198   // 64 + 3 + 128 + 3

// ---------------------------------------------------------------------------
// Single fused kernel (R18 = R17 + M=8 coarsening + v_min3 scan).
// Blocks [0,256): knn over 512 points each + gather of cols 67..197.
//   Phase A: value-only min scan: wave w scans slice [256w,256w+256) for the
//     block's 512 points (M=8/lane). Key d = 3-fma chain (text identical
//     since R3, bit-exact across 13 passing rounds); accumulate with
//     min3(d0,d1,best) — min is order-independent & exact, value unchanged.
//   Phase B: per-point min over 8 slice minima (strict < => lowest slice).
//   Phase C: per-wave compact + rescue scan (verbatim R16 machinery) ->
//     winner into s_idx.
//   Phase D: phase-split gather of cols 67..197 (P1 LDS idx / P2 VMEM
//     gathers / P3 coalesced stores), e-linear decode, 512x131 elems.
// Blocks [256,512): idx-independent copy (cols 0..66, zeros, batch; R14).
// LDS ~68KB -> 2 blocks/CU (16 waves/CU, 4/SIMD).
// ---------------------------------------------------------------------------
__global__ __launch_bounds__(512, 2) void fused_kernel(
    const float* __restrict__ pos_hr,   // [NB*NH, 3]
    const float* __restrict__ pos_lr,   // [NB*NL, 3]
    const float* __restrict__ x_hr,     // [NB*NH, 64]
    const float* __restrict__ x_lr,     // [NB*NL, 128]
    float* __restrict__ out)
{
    __shared__ float4 cand[NL];         // 32 KiB (x, y, z, 0.5*|p|^2)
    __shared__ float  pval[8][512];     // 16 KiB per-slice min value
    __shared__ float  gminL[512];       //  2 KiB global min per point
    __shared__ int    winw[512];        //  2 KiB winning slice per point
    __shared__ short  plist[8][512];    //  8 KiB per-wave compacted points
    __shared__ float  phsx[512], phsy[512], phsz[512];   // 6 KiB staged ph
    __shared__ int    s_idx[512];       //  2 KiB final winner (global lr row)

    if (blockIdx.x < 256) {
        // ----------------------------- knn role -----------------------------
        const int b  = blockIdx.x >> 5;     // 32 blocks per batch
        const int p0 = blockIdx.x << 9;     // first global point (512/block)
        const int w  = threadIdx.x >> 6;    // wave id = candidate slice
        const int l  = threadIdx.x & 63;

        const float* pl = pos_lr + (size_t)b * NL * 3;
        for (int j = threadIdx.x; j < NL; j += 512) {
            float x = pl[j * 3 + 0];
            float y = pl[j * 3 + 1];
            float z = pl[j * 3 + 2];
            cand[j] = make_float4(x, y, z, 0.5f * ((x * x + y * y) + z * z));
        }

        // M=8 points per lane (lane-stride 64 within the block's 512 points)
        float phx[8], phy[8], phz[8];
#pragma unroll
        for (int m = 0; m < 8; ++m) {
            const int pt = p0 + (m << 6) + l;
            phx[m] = pos_hr[pt * 3 + 0];
            phy[m] = pos_hr[pt * 3 + 1];
            phz[m] = pos_hr[pt * 3 + 2];
        }
        if (w == 0) {                        // stage ph for the rescue phase
#pragma unroll
            for (int m = 0; m < 8; ++m) {
                const int ptl = (m << 6) + l;
                phsx[ptl] = phx[m]; phsy[ptl] = phy[m]; phsz[ptl] = phz[m];
            }
        }
        __syncthreads();

        // Phase A: value-only scan, min3 accumulate
        float best[8];
#pragma unroll
        for (int m = 0; m < 8; ++m) best[m] = 3.4e38f;

        const int base = w << 8;            // slice start (batch-local)
        for (int j = 0; j < 256; j += 2) {
            const float4 c0 = cand[base + j];
            const float4 c1 = cand[base + j + 1];
#pragma unroll
            for (int m = 0; m < 8; ++m) {
                float d0 = fmaf(-phz[m], c0.z, fmaf(-phy[m], c0.y, fmaf(-phx[m], c0.x, c0.w)));
                float d1 = fmaf(-phz[m], c1.z, fmaf(-phy[m], c1.y, fmaf(-phx[m], c1.x, c1.w)));
                best[m] = fminf(fminf(d0, d1), best[m]);   // -> v_min3_f32
            }
        }
#pragma unroll
        for (int m = 0; m < 8; ++m)
            pval[w][(m << 6) + l] = best[m];
        __syncthreads();

        // Phase B: per-point min over slices; strict < keeps lowest slice
        {
            const int t = threadIdx.x;
            float g = pval[0][t]; int ww = 0;
#pragma unroll
            for (int q = 1; q < 8; ++q) {
                const float qv = pval[q][t];
                if (qv < g) { g = qv; ww = q; }
            }
            gminL[t] = g; winw[t] = ww;
        }
        __syncthreads();

        // Phase C: compact points this wave won, then index-rescue scan
        int cnt = 0;
#pragma unroll
        for (int m = 0; m < 8; ++m) {
            const int pt = (m << 6) + l;
            const bool pred = (winw[pt] == w);
            const unsigned long long mask = __ballot(pred);
            const int pos = __popcll(mask & ((1ull << l) - 1ull));
            if (pred) plist[w][cnt + pos] = (short)pt;
            cnt += __popcll(mask);
        }

        for (int i = 0; i < cnt; ++i) {
            const int pt = plist[w][i];
            const float qx = phsx[pt], qy = phsy[pt], qz = phsz[pt];
            const float g  = gminL[pt];
            int loc = 4;
#pragma unroll
            for (int k = 3; k >= 0; --k) {      // descending: final loc = lowest k
                const float4 c = cand[base + (l << 2) + k];
                const float d = fmaf(-qz, c.z, fmaf(-qy, c.y, fmaf(-qx, c.x, c.w)));
                if (d == g) loc = k;            // bit-exact recompute
            }
            const unsigned long long mk = __ballot(loc < 4);
            if (mk) {
                const int firstlane = __ffsll((unsigned long long)mk) - 1;
                const int locf = __shfl(loc, firstlane);
                if (l == 0)
                    s_idx[pt] = b * NL + base + (firstlane << 2) + locf;
            }
        }
        __syncthreads();

        // Phase D: gather cols 67..197 for rows p0..p0+511.
        // 512*131 = 67072 elems, stride 512 => 131 iters = 11 batches x 12
        // (last batch guarded). Decode: 512 = 3*131 + 119.
        {
            const int tid = threadIdx.x;
            int rl = tid / 131;
            int c  = tid - rl * 131;
            for (int t = 0; t < 11; ++t) {
                int rs[12], cs[12], ls[12];
                float vs[12];
#pragma unroll
                for (int k = 0; k < 12; ++k) {
                    rs[k] = rl; cs[k] = c;
                    ls[k] = s_idx[rl < 512 ? rl : 511];
                    c += 119;
                    const int carry = (c >= 131) ? 1 : 0;
                    c -= carry ? 131 : 0;
                    rl += 3 + carry;
                }
#pragma unroll
                for (int k = 0; k < 12; ++k) {
                    const int cc = cs[k];
                    const float* a = (cc < F_LR) ? x_lr   + ls[k] * F_LR + cc
                                                 : pos_lr + ls[k] * 3    + (cc - F_LR);
                    vs[k] = *a;
                }
#pragma unroll
                for (int k = 0; k < 12; ++k) {
                    if (t == 10) {
                        const int i = tid + (t * 12 + k) * 512;
                        if (i >= 512 * 131) continue;
                    }
                    out[(size_t)(p0 + rs[k]) * OUT_COLS + 67 + cs[k]] = vs[k];
                }
            }
        }
    } else {
        // ----------------------------- copy role ----------------------------
        const int cb = blockIdx.x - 256;    // [0,256)
        const int r0 = cb << 9;             // 512 rows per block

#pragma unroll 4
        for (int e = threadIdx.x; e < 512 * 67; e += 512) {
            const int rl  = e / 67;
            const int c   = e - rl * 67;
            const int row = r0 + rl;
            const float v = (c < F_HR) ? x_hr[(row << 6) + c]
                                       : pos_hr[row * 3 + (c - F_HR)];
            out[row * OUT_COLS + c] = v;
        }

        const int R0 = NB * NH * OUT_COLS;  // 25,952,256
        const int Z  = NB * NH * 3;         // 393,216
        const int z0 = cb << 11;
#pragma unroll
        for (int e = threadIdx.x; e < 2048; e += 512) {
            const int i = z0 + e;
            out[R0 + i] = (i < Z) ? 0.0f : (float)((i - Z) >> 14);  // NH = 2^14
        }
    }
}

extern "C" void kernel_launch(void* const* d_in, const int* in_sizes, int n_in,
                              void* d_out, int out_size, void* d_ws, size_t ws_size,
                              hipStream_t stream) {
    const float* x_hr   = (const float*)d_in[0];
    const float* pos_hr = (const float*)d_in[1];
    // d_in[2] = batch_hr (int32) — unused, batch is contiguous repeats
    const float* x_lr   = (const float*)d_in[3];
    const float* pos_lr = (const float*)d_in[4];
    // d_in[5] = batch_lr (int32) — unused

    fused_kernel<<<dim3(512), dim3(512), 0, stream>>>(
        pos_hr, pos_lr, x_hr, x_lr, (float*)d_out);
}

// Round 19
// 55.688 us; speedup vs baseline: 1.2134x; 1.2134x over previous
//
#include <hip/hip_runtime.h>

#define NB    8
#define NH    16384
#define NL    2048
#define F_HR  64
#define F_LR  128
#define OUT_COLS 198   // 64 + 3 + 128 + 3

// ---------------------------------------------------------------------------
// Single fused kernel — R17 structure (proven 54.8us) + v_min3 scan.
// Blocks [0,512): knn (M=4, 8 slices) + gather of cols 67..197.
//   Phase A: value-only min scan; key d = 3-fma chain (text identical since
//     R3, bit-exact across 14 passing rounds); accumulate min3(d0,d1,best)
//     — min is order-independent & exact, so the final min VALUE is
//     bit-identical to the 2-slot version (R18 post-mortem: M=4 scan is
//     VALU-floored at 4 ops/pair; min3 cuts it to 3.5; M=8's occupancy
//     collapse refuted, reverted).
//   Phase B: per-point min over 8 slice minima (strict < => lowest slice).
//   Phase C: per-wave compact + rescue scan -> winner into s_idx (LDS).
//   Phase D: phase-split gather of cols 67..197 (P1 LDS idx / P2 VMEM
//     gathers / P3 coalesced stores), e-linear decode, 256x131 elems.
// Blocks [512,768): idx-independent copy (cols 0..66, zeros, batch; R14).
// LDS 51KB -> 3 blocks/CU, 24 waves/CU.
// ---------------------------------------------------------------------------
__global__ __launch_bounds__(512, 4) void fused_kernel(
    const float* __restrict__ pos_hr,   // [NB*NH, 3]
    const float* __restrict__ pos_lr,   // [NB*NL, 3]
    const float* __restrict__ x_hr,     // [NB*NH, 64]
    const float* __restrict__ x_lr,     // [NB*NL, 128]
    float* __restrict__ out)
{
    __shared__ float4 cand[NL];         // 32 KiB (x, y, z, 0.5*|p|^2)
    __shared__ float  pval[8][256];     //  8 KiB per-slice min value
    __shared__ float  gminL[256];       //  1 KiB global min per point
    __shared__ int    winw[256];        //  1 KiB winning slice per point
    __shared__ short  plist[8][256];    //  4 KiB per-wave compacted points
    __shared__ float  phsx[256], phsy[256], phsz[256];   // 3 KiB staged ph
    __shared__ int    s_idx[256];       //  1 KiB final winner (global lr row)

    if (blockIdx.x < 512) {
        // ----------------------------- knn role -----------------------------
        const int b  = blockIdx.x >> 6;     // 64 blocks per batch
        const int p0 = blockIdx.x << 8;     // first global point of this block
        const int w  = threadIdx.x >> 6;    // wave id = candidate slice
        const int l  = threadIdx.x & 63;

        const float* pl = pos_lr + (size_t)b * NL * 3;
        for (int j = threadIdx.x; j < NL; j += 512) {
            float x = pl[j * 3 + 0];
            float y = pl[j * 3 + 1];
            float z = pl[j * 3 + 2];
            cand[j] = make_float4(x, y, z, 0.5f * ((x * x + y * y) + z * z));
        }

        float phx[4], phy[4], phz[4];
#pragma unroll
        for (int m = 0; m < 4; ++m) {
            const int pt = p0 + (m << 6) + l;
            phx[m] = pos_hr[pt * 3 + 0];
            phy[m] = pos_hr[pt * 3 + 1];
            phz[m] = pos_hr[pt * 3 + 2];
        }
        if (w == 0) {                        // stage ph for the rescue phase
#pragma unroll
            for (int m = 0; m < 4; ++m) {
                const int ptl = (m << 6) + l;
                phsx[ptl] = phx[m]; phsy[ptl] = phy[m]; phsz[ptl] = phz[m];
            }
        }
        __syncthreads();

        // Phase A: value-only scan, min3 accumulate (1 op per 2 cands saved)
        float best[4];
#pragma unroll
        for (int m = 0; m < 4; ++m) best[m] = 3.4e38f;

        const int base = w << 8;            // slice start (batch-local)
        for (int j = 0; j < 256; j += 2) {
            const float4 c0 = cand[base + j];
            const float4 c1 = cand[base + j + 1];
#pragma unroll
            for (int m = 0; m < 4; ++m) {
                float d0 = fmaf(-phz[m], c0.z, fmaf(-phy[m], c0.y, fmaf(-phx[m], c0.x, c0.w)));
                float d1 = fmaf(-phz[m], c1.z, fmaf(-phy[m], c1.y, fmaf(-phx[m], c1.x, c1.w)));
                best[m] = fminf(fminf(d0, d1), best[m]);   // -> v_min3_f32
            }
        }
#pragma unroll
        for (int m = 0; m < 4; ++m)
            pval[w][(m << 6) + l] = best[m];
        __syncthreads();

        // Phase B: per-point min over slices; strict < keeps lowest slice
        if (threadIdx.x < 256) {
            const int t = threadIdx.x;
            float g = pval[0][t]; int ww = 0;
#pragma unroll
            for (int q = 1; q < 8; ++q) {
                const float qv = pval[q][t];
                if (qv < g) { g = qv; ww = q; }
            }
            gminL[t] = g; winw[t] = ww;
        }
        __syncthreads();

        // Phase C: compact points this wave won, then index-rescue scan
        int cnt = 0;
#pragma unroll
        for (int m = 0; m < 4; ++m) {
            const int pt = (m << 6) + l;
            const bool pred = (winw[pt] == w);
            const unsigned long long mask = __ballot(pred);
            const int pos = __popcll(mask & ((1ull << l) - 1ull));
            if (pred) plist[w][cnt + pos] = (short)pt;
            cnt += __popcll(mask);
        }

        for (int i = 0; i < cnt; ++i) {
            const int pt = plist[w][i];
            const float qx = phsx[pt], qy = phsy[pt], qz = phsz[pt];
            const float g  = gminL[pt];
            int loc = 4;
#pragma unroll
            for (int k = 3; k >= 0; --k) {      // descending: final loc = lowest k
                const float4 c = cand[base + (l << 2) + k];
                const float d = fmaf(-qz, c.z, fmaf(-qy, c.y, fmaf(-qx, c.x, c.w)));
                if (d == g) loc = k;            // bit-exact recompute
            }
            const unsigned long long mk = __ballot(loc < 4);
            if (mk) {
                const int firstlane = __ffsll((unsigned long long)mk) - 1;
                const int locf = __shfl(loc, firstlane);
                if (l == 0)
                    s_idx[pt] = b * NL + base + (firstlane << 2) + locf;
            }
        }
        __syncthreads();

        // Phase D: gather cols 67..197 for rows p0..p0+255.
        // e-linear over 256*131 = 33536 elems; 66 = 6*11 iters; e = tid+n*512,
        // decode rl = e/131, c = e%131 incrementally (512 = 3*131 + 119).
        {
            const int tid = threadIdx.x;
            int rl = tid / 131;
            int c  = tid - rl * 131;
            for (int t = 0; t < 11; ++t) {
                int rs[6], cs[6], ls[6];
                float vs[6];
#pragma unroll
                for (int k = 0; k < 6; ++k) {
                    rs[k] = rl; cs[k] = c;
                    ls[k] = s_idx[rl < 256 ? rl : 255];
                    c += 119;
                    const int carry = (c >= 131) ? 1 : 0;
                    c -= carry ? 131 : 0;
                    rl += 3 + carry;
                }
#pragma unroll
                for (int k = 0; k < 6; ++k) {
                    const int cc = cs[k];
                    const float* a = (cc < F_LR) ? x_lr   + ls[k] * F_LR + cc
                                                 : pos_lr + ls[k] * 3    + (cc - F_LR);
                    vs[k] = *a;
                }
#pragma unroll
                for (int k = 0; k < 6; ++k) {
                    if (t == 10 && k == 5 && tid + 33280 >= 33536) continue;  // guard
                    out[(size_t)(p0 + rs[k]) * OUT_COLS + 67 + cs[k]] = vs[k];
                }
            }
        }
    } else {
        // ----------------------------- copy role ----------------------------
        const int cb = blockIdx.x - 512;    // [0,256)
        const int r0 = cb << 9;             // 512 rows per block

#pragma unroll 4
        for (int e = threadIdx.x; e < 512 * 67; e += 512) {
            const int rl  = e / 67;
            const int c   = e - rl * 67;
            const int row = r0 + rl;
            const float v = (c < F_HR) ? x_hr[(row << 6) + c]
                                       : pos_hr[row * 3 + (c - F_HR)];
            out[row * OUT_COLS + c] = v;
        }

        const int R0 = NB * NH * OUT_COLS;  // 25,952,256
        const int Z  = NB * NH * 3;         // 393,216
        const int z0 = cb << 11;
#pragma unroll
        for (int e = threadIdx.x; e < 2048; e += 512) {
            const int i = z0 + e;
            out[R0 + i] = (i < Z) ? 0.0f : (float)((i - Z) >> 14);  // NH = 2^14
        }
    }
}

extern "C" void kernel_launch(void* const* d_in, const int* in_sizes, int n_in,
                              void* d_out, int out_size, void* d_ws, size_t ws_size,
                              hipStream_t stream) {
    const float* x_hr   = (const float*)d_in[0];
    const float* pos_hr = (const float*)d_in[1];
    // d_in[2] = batch_hr (int32) — unused, batch is contiguous repeats
    const float* x_lr   = (const float*)d_in[3];
    const float* pos_lr = (const float*)d_in[4];
    // d_in[5] = batch_lr (int32) — unused

    fused_kernel<<<dim3(768), dim3(512), 0, stream>>>(
        pos_hr, pos_lr, x_hr, x_lr, (float*)d_out);
}

// Round 20
// 54.321 us; speedup vs baseline: 1.2440x; 1.0252x over previous
//
#include <hip/hip_runtime.h>

#define NB    8
#define NH    16384
#define NL    2048
#define F_HR  64
#define F_LR  128
#define OUT_COLS 198   // 64 + 3 + 128 + 3

// ---------------------------------------------------------------------------
// Single fused kernel — R17/R19 structure + scan j-loop unroll 4.
// R19 post-mortem: scan is ~40us vs ~14us issue-bound model -> latency-
// exposed (per-iter {2 ds_read -> wait -> 28 VALU} leaves ~120cyc LDS
// latency only partly covered at 4 waves/SIMD). unroll 4 batches 8 reads
// per wait window so the compiler can software-pipeline (counted lgkmcnt),
// without R12's manual-copy overhead. Everything else proven & unchanged.
// Blocks [0,512): knn (M=4, 8 slices) + gather cols 67..197.
// Blocks [512,768): idx-independent copy (cols 0..66, zeros, batch).
// LDS 51KB -> 3 blocks/CU co-residency for the copy-overlap window.
// ---------------------------------------------------------------------------
__global__ __launch_bounds__(512, 4) void fused_kernel(
    const float* __restrict__ pos_hr,   // [NB*NH, 3]
    const float* __restrict__ pos_lr,   // [NB*NL, 3]
    const float* __restrict__ x_hr,     // [NB*NH, 64]
    const float* __restrict__ x_lr,     // [NB*NL, 128]
    float* __restrict__ out)
{
    __shared__ float4 cand[NL];         // 32 KiB (x, y, z, 0.5*|p|^2)
    __shared__ float  pval[8][256];     //  8 KiB per-slice min value
    __shared__ float  gminL[256];       //  1 KiB global min per point
    __shared__ int    winw[256];        //  1 KiB winning slice per point
    __shared__ short  plist[8][256];    //  4 KiB per-wave compacted points
    __shared__ float  phsx[256], phsy[256], phsz[256];   // 3 KiB staged ph
    __shared__ int    s_idx[256];       //  1 KiB final winner (global lr row)

    if (blockIdx.x < 512) {
        // ----------------------------- knn role -----------------------------
        const int b  = blockIdx.x >> 6;     // 64 blocks per batch
        const int p0 = blockIdx.x << 8;     // first global point of this block
        const int w  = threadIdx.x >> 6;    // wave id = candidate slice
        const int l  = threadIdx.x & 63;

        const float* pl = pos_lr + (size_t)b * NL * 3;
#pragma unroll
        for (int j = threadIdx.x; j < NL; j += 512) {
            float x = pl[j * 3 + 0];
            float y = pl[j * 3 + 1];
            float z = pl[j * 3 + 2];
            cand[j] = make_float4(x, y, z, 0.5f * ((x * x + y * y) + z * z));
        }

        float phx[4], phy[4], phz[4];
#pragma unroll
        for (int m = 0; m < 4; ++m) {
            const int pt = p0 + (m << 6) + l;
            phx[m] = pos_hr[pt * 3 + 0];
            phy[m] = pos_hr[pt * 3 + 1];
            phz[m] = pos_hr[pt * 3 + 2];
        }
        if (w == 0) {                        // stage ph for the rescue phase
#pragma unroll
            for (int m = 0; m < 4; ++m) {
                const int ptl = (m << 6) + l;
                phsx[ptl] = phx[m]; phsy[ptl] = phy[m]; phsz[ptl] = phz[m];
            }
        }
        __syncthreads();

        // Phase A: value-only scan, min3 accumulate, unroll 4 (8 reads/window)
        float best[4];
#pragma unroll
        for (int m = 0; m < 4; ++m) best[m] = 3.4e38f;

        const int base = w << 8;            // slice start (batch-local)
#pragma unroll 4
        for (int j = 0; j < 256; j += 2) {
            const float4 c0 = cand[base + j];
            const float4 c1 = cand[base + j + 1];
#pragma unroll
            for (int m = 0; m < 4; ++m) {
                float d0 = fmaf(-phz[m], c0.z, fmaf(-phy[m], c0.y, fmaf(-phx[m], c0.x, c0.w)));
                float d1 = fmaf(-phz[m], c1.z, fmaf(-phy[m], c1.y, fmaf(-phx[m], c1.x, c1.w)));
                best[m] = fminf(fminf(d0, d1), best[m]);   // -> v_min3_f32
            }
        }
#pragma unroll
        for (int m = 0; m < 4; ++m)
            pval[w][(m << 6) + l] = best[m];
        __syncthreads();

        // Phase B: per-point min over slices; strict < keeps lowest slice
        if (threadIdx.x < 256) {
            const int t = threadIdx.x;
            float g = pval[0][t]; int ww = 0;
#pragma unroll
            for (int q = 1; q < 8; ++q) {
                const float qv = pval[q][t];
                if (qv < g) { g = qv; ww = q; }
            }
            gminL[t] = g; winw[t] = ww;
        }
        __syncthreads();

        // Phase C: compact points this wave won, then index-rescue scan
        int cnt = 0;
#pragma unroll
        for (int m = 0; m < 4; ++m) {
            const int pt = (m << 6) + l;
            const bool pred = (winw[pt] == w);
            const unsigned long long mask = __ballot(pred);
            const int pos = __popcll(mask & ((1ull << l) - 1ull));
            if (pred) plist[w][cnt + pos] = (short)pt;
            cnt += __popcll(mask);
        }

        for (int i = 0; i < cnt; ++i) {
            const int pt = plist[w][i];
            const float qx = phsx[pt], qy = phsy[pt], qz = phsz[pt];
            const float g  = gminL[pt];
            int loc = 4;
#pragma unroll
            for (int k = 3; k >= 0; --k) {      // descending: final loc = lowest k
                const float4 c = cand[base + (l << 2) + k];
                const float d = fmaf(-qz, c.z, fmaf(-qy, c.y, fmaf(-qx, c.x, c.w)));
                if (d == g) loc = k;            // bit-exact recompute
            }
            const unsigned long long mk = __ballot(loc < 4);
            if (mk) {
                const int firstlane = __ffsll((unsigned long long)mk) - 1;
                const int locf = __shfl(loc, firstlane);
                if (l == 0)
                    s_idx[pt] = b * NL + base + (firstlane << 2) + locf;
            }
        }
        __syncthreads();

        // Phase D: gather cols 67..197 for rows p0..p0+255.
        // e-linear over 256*131 = 33536 elems; 66 = 6*11 iters; e = tid+n*512,
        // decode rl = e/131, c = e%131 incrementally (512 = 3*131 + 119).
        {
            const int tid = threadIdx.x;
            int rl = tid / 131;
            int c  = tid - rl * 131;
            for (int t = 0; t < 11; ++t) {
                int rs[6], cs[6], ls[6];
                float vs[6];
#pragma unroll
                for (int k = 0; k < 6; ++k) {
                    rs[k] = rl; cs[k] = c;
                    ls[k] = s_idx[rl < 256 ? rl : 255];
                    c += 119;
                    const int carry = (c >= 131) ? 1 : 0;
                    c -= carry ? 131 : 0;
                    rl += 3 + carry;
                }
#pragma unroll
                for (int k = 0; k < 6; ++k) {
                    const int cc = cs[k];
                    const float* a = (cc < F_LR) ? x_lr   + ls[k] * F_LR + cc
                                                 : pos_lr + ls[k] * 3    + (cc - F_LR);
                    vs[k] = *a;
                }
#pragma unroll
                for (int k = 0; k < 6; ++k) {
                    if (t == 10 && k == 5 && tid + 33280 >= 33536) continue;  // guard
                    out[(size_t)(p0 + rs[k]) * OUT_COLS + 67 + cs[k]] = vs[k];
                }
            }
        }
    } else {
        // ----------------------------- copy role ----------------------------
        const int cb = blockIdx.x - 512;    // [0,256)
        const int r0 = cb << 9;             // 512 rows per block

#pragma unroll 4
        for (int e = threadIdx.x; e < 512 * 67; e += 512) {
            const int rl  = e / 67;
            const int c   = e - rl * 67;
            const int row = r0 + rl;
            const float v = (c < F_HR) ? x_hr[(row << 6) + c]
                                       : pos_hr[row * 3 + (c - F_HR)];
            out[row * OUT_COLS + c] = v;
        }

        const int R0 = NB * NH * OUT_COLS;  // 25,952,256
        const int Z  = NB * NH * 3;         // 393,216
        const int z0 = cb << 11;
#pragma unroll
        for (int e = threadIdx.x; e < 2048; e += 512) {
            const int i = z0 + e;
            out[R0 + i] = (i < Z) ? 0.0f : (float)((i - Z) >> 14);  // NH = 2^14
        }
    }
}

extern "C" void kernel_launch(void* const* d_in, const int* in_sizes, int n_in,
                              void* d_out, int out_size, void* d_ws, size_t ws_size,
                              hipStream_t stream) {
    const float* x_hr   = (const float*)d_in[0];
    const float* pos_hr = (const float*)d_in[1];
    // d_in[2] = batch_hr (int32) — unused, batch is contiguous repeats
    const float* x_lr   = (const float*)d_in[3];
    const float* pos_lr = (const float*)d_in[4];
    // d_in[5] = batch_lr (int32) — unused

    fused_kernel<<<dim3(768), dim3(512), 0, stream>>>(
        pos_hr, pos_lr, x_hr, x_lr, (float*)d_out);
}